// Round 4
// baseline (235.429 us; speedup 1.0000x reference)
//
#include <hip/hip_runtime.h>
#include <hip/hip_bf16.h>
#include <math.h>

#define NROWS 131072   // B*T = 32*4096
#define KC    512      // codebook size
#define DD    64       // embedding dim
#define NELEM (NROWS * DD)

#define OUT_IDX_OFF  NELEM
#define OUT_LOSS_OFF (NELEM + NROWS)

#define MARGIN 3e-5f   // same as the passing round (bit-identical screen math)

// d_ws byte offsets
#define WSO_CNT   0                       // int   flagged-row count
#define WSO_LOSS  8                       // float loss accumulator
#define WSO_DONE  16                      // int   refine done-counter
#define WSO_WNORM 64                      // float wnorm_np[512]
#define WSO_LIST  4096                    // int   flagList[NROWS]

typedef __attribute__((ext_vector_type(8))) short short8;
typedef __attribute__((ext_vector_type(4))) float f32x4;

// ---------------------------------------------------------------------------
// bf16 helpers (RNE via __float2bfloat16)
// ---------------------------------------------------------------------------
static __device__ __forceinline__ short f2bf(float f) {
  __hip_bfloat16 h = __float2bfloat16(f);
  short s; __builtin_memcpy(&s, &h, 2); return s;
}
static __device__ __forceinline__ float bf2f(short s) {
  unsigned u = ((unsigned)(unsigned short)s) << 16;
  float f; __builtin_memcpy(&f, &u, 4); return f;
}
// split 8 f32 (in regs) into bf16 hi + bf16 lo(residual)
static __device__ __forceinline__ void split8(const float* v, short8& hi, short8& lo) {
#pragma unroll
  for (int j = 0; j < 8; j++) {
    float f = v[j];
    short hb = f2bf(f);
    float r = f - bf2f(hb);
    hi[j] = hb;
    lo[j] = f2bf(r);
  }
}

// ---------------------------------------------------------------------------
// numpy's pairwise sum of squares for 64 contiguous f32 (8-accumulator tree).
// contract(off) REQUIRED (hipcc default -ffp-contract=fast would fuse).
// ---------------------------------------------------------------------------
__device__ __forceinline__ float np_sumsq64(const float* __restrict__ p) {
#pragma clang fp contract(off)
  float r0 = p[0] * p[0], r1 = p[1] * p[1], r2 = p[2] * p[2], r3 = p[3] * p[3];
  float r4 = p[4] * p[4], r5 = p[5] * p[5], r6 = p[6] * p[6], r7 = p[7] * p[7];
  for (int i = 8; i < 64; i += 8) {
    r0 = r0 + p[i + 0] * p[i + 0];
    r1 = r1 + p[i + 1] * p[i + 1];
    r2 = r2 + p[i + 2] * p[i + 2];
    r3 = r3 + p[i + 3] * p[i + 3];
    r4 = r4 + p[i + 4] * p[i + 4];
    r5 = r5 + p[i + 5] * p[i + 5];
    r6 = r6 + p[i + 6] * p[i + 6];
    r7 = r7 + p[i + 7] * p[i + 7];
  }
  return ((r0 + r1) + (r2 + r3)) + ((r4 + r5) + (r6 + r7));
}

// ---------------------------------------------------------------------------
// Kernel 1 (k_main): fused screen + argmin + epilogue. 32 rows/wave (2 M-tiles)
// -> 4096 waves = 4 waves/SIMD for latency hiding. B-fragments loaded directly
// from W (no prep kernel): lane L needs W[t*16+(L&15)][32h+(L>>4)*8+j], j=0..7
// = contiguous 8 floats = 2x float4; converted to bf16 hi/lo in-register.
// wn (screening ||w||^2) from the same floats via quad butterfly (identical
// across waves; differs from numpy wnorm by <=1ulp of ~8e-5 — covered by
// MARGIN). MFMA chain order per accumulator identical to the passing round.
// Block 0 additionally computes numpy-exact wnorm[512] for the refine pass.
// ---------------------------------------------------------------------------
__global__ __launch_bounds__(256) void k_main(
    const float* __restrict__ z, const float* __restrict__ W,
    float* __restrict__ out, float* __restrict__ wnorm,
    int* __restrict__ flagList, int* __restrict__ flagCnt,
    float* __restrict__ lossSum) {
  const int tid = threadIdx.x;
  const int lane = tid & 63;
  const int wv = tid >> 6;
  const int rowBase = blockIdx.x * 128 + wv * 32;
  const int m = lane & 15, quad = lane >> 4;

  if (blockIdx.x == 0) {
    wnorm[tid] = np_sumsq64(W + (tid << 6));
    wnorm[tid + 256] = np_sumsq64(W + ((tid + 256) << 6));
  }

  // ---- A fragments: z hi/lo for 2 M-tiles x 2 k-halves ----
  short8 Ah[2][2], Al[2][2];
#pragma unroll
  for (int mt = 0; mt < 2; mt++) {
    const float* zp = z + (size_t)(rowBase + (mt << 4) + m) * DD + (quad << 3);
#pragma unroll
    for (int h = 0; h < 2; h++) {
      float4 u0 = *(const float4*)(zp + (h << 5));
      float4 u1 = *(const float4*)(zp + (h << 5) + 4);
      float v[8] = {u0.x, u0.y, u0.z, u0.w, u1.x, u1.y, u1.z, u1.w};
      split8(v, Ah[mt][h], Al[mt][h]);
    }
  }

  float b1[2][4], b2[2][4];
  int bi[2][4];
#pragma unroll
  for (int mt = 0; mt < 2; mt++)
#pragma unroll
    for (int r = 0; r < 4; r++) { b1[mt][r] = 1e30f; b2[mt][r] = 1e30f; bi[mt][r] = 0; }

  // ---- main loop over 32 codeword tiles ----
  const float* wbase = W + (size_t)(m << 6) + (quad << 3);
  for (int t = 0; t < 32; t++) {
    const float* wp = wbase + (size_t)t * (16 * DD);
    float4 a0 = *(const float4*)(wp);
    float4 a1 = *(const float4*)(wp + 4);
    float4 c0 = *(const float4*)(wp + 32);
    float4 c1 = *(const float4*)(wp + 36);
    float v0[8] = {a0.x, a0.y, a0.z, a0.w, a1.x, a1.y, a1.z, a1.w};
    float v1[8] = {c0.x, c0.y, c0.z, c0.w, c1.x, c1.y, c1.z, c1.w};

    // wn = ||w_cw||^2 (quad butterfly; deterministic, wave-independent)
    float p = 0.f;
#pragma unroll
    for (int j = 0; j < 8; j++) p = fmaf(v0[j], v0[j], p);
#pragma unroll
    for (int j = 0; j < 8; j++) p = fmaf(v1[j], v1[j], p);
    p += __shfl_xor(p, 16, 64);
    p += __shfl_xor(p, 32, 64);

    short8 Bh[2], Bl[2];
    split8(v0, Bh[0], Bl[0]);
    split8(v1, Bh[1], Bl[1]);

    f32x4 acc[2] = {{0.f, 0.f, 0.f, 0.f}, {0.f, 0.f, 0.f, 0.f}};
#pragma unroll
    for (int h = 0; h < 2; h++) {
#pragma unroll
      for (int mt = 0; mt < 2; mt++)
        acc[mt] = __builtin_amdgcn_mfma_f32_16x16x32_bf16(Ah[mt][h], Bh[h], acc[mt], 0, 0, 0);
#pragma unroll
      for (int mt = 0; mt < 2; mt++)
        acc[mt] = __builtin_amdgcn_mfma_f32_16x16x32_bf16(Al[mt][h], Bh[h], acc[mt], 0, 0, 0);
#pragma unroll
      for (int mt = 0; mt < 2; mt++)
        acc[mt] = __builtin_amdgcn_mfma_f32_16x16x32_bf16(Ah[mt][h], Bl[h], acc[mt], 0, 0, 0);
    }

    int colv = (t << 4) + m;
#pragma unroll
    for (int mt = 0; mt < 2; mt++)
#pragma unroll
      for (int r = 0; r < 4; r++) {
        float s = fmaf(-2.0f, acc[mt][r], p);
        if (s < b1[mt][r]) { b2[mt][r] = b1[mt][r]; b1[mt][r] = s; bi[mt][r] = colv; }
        else b2[mt][r] = fminf(b2[mt][r], s);
      }
  }

  // ---- merge across the 16 col-lanes ----
#pragma unroll
  for (int off = 1; off < 16; off <<= 1) {
#pragma unroll
    for (int mt = 0; mt < 2; mt++)
#pragma unroll
      for (int r = 0; r < 4; r++) {
        float o1 = __shfl_xor(b1[mt][r], off, 64);
        float o2 = __shfl_xor(b2[mt][r], off, 64);
        int oi = __shfl_xor(bi[mt][r], off, 64);
        if (o1 < b1[mt][r] || (o1 == b1[mt][r] && oi < bi[mt][r])) {
          b2[mt][r] = fminf(b1[mt][r], o2);
          b1[mt][r] = o1; bi[mt][r] = oi;
        } else {
          b2[mt][r] = fminf(b2[mt][r], o1);
        }
      }
  }

  // ---- fused epilogue for this wave's 32 rows ----
  float lossAcc = 0.f;
#pragma unroll
  for (int mt = 0; mt < 2; mt++)
#pragma unroll
    for (int lr = 0; lr < 16; lr++) {
      const int q = lr >> 2, r = lr & 3;
      int ki = __shfl(bi[mt][r], q << 4, 64);
      float gap = b2[mt][r] - b1[mt][r];
      float gapr = __shfl(gap, q << 4, 64);
      int row = rowBase + (mt << 4) + lr;
      float zv = z[(size_t)row * DD + lane];
      float w = W[(ki << 6) + lane];
      float tt = w - zv;
      float o = zv + tt;  // matches reference z + (z_q - z)
      out[(size_t)row * DD + lane] = o;
      float dl = zv - o;
      lossAcc = fmaf(dl, dl, lossAcc);
      if (lane == 0) {
        out[OUT_IDX_OFF + row] = (float)ki;
        if (gapr < MARGIN) {
          int slot = atomicAdd(flagCnt, 1);
          flagList[slot] = row;
        }
      }
    }

#pragma unroll
  for (int off = 1; off < 64; off <<= 1) lossAcc += __shfl_xor(lossAcc, off, 64);
  if (lane == 0) atomicAdd(lossSum, lossAcc);
}

// ---------------------------------------------------------------------------
// Kernel 2 (k_refine): numpy-f32 replication for flagged rows + out/loss patch
// + fused loss finalize via done-counter (last block writes out[LOSS]).
// ---------------------------------------------------------------------------
__global__ void k_refine(const float* __restrict__ z, const float* __restrict__ W,
                         const float* __restrict__ wnp, float* __restrict__ out,
                         const int* __restrict__ flagList,
                         const int* __restrict__ flagCnt,
                         float* __restrict__ lossSum, int* __restrict__ doneCnt) {
  int nflag = *flagCnt;
  int lane = threadIdx.x & 63;
  int wave = (blockIdx.x * blockDim.x + threadIdx.x) >> 6;
  int nWaves = (gridDim.x * blockDim.x) >> 6;

  for (int f = wave; f < nflag; f += nWaves) {
    int row = flagList[f];
    const float* zr = z + (size_t)row * DD;
    float A = np_sumsq64(zr);

    float best = 1e30f;
    int bk = 0x7fffffff;
#pragma unroll
    for (int j = 0; j < KC / 64; j++) {
      int k = lane + (j << 6);
      const float* wk = W + (k << 6);
      double cd = 0.0;
      for (int d = 0; d < DD; d++) cd = fma((double)zr[d], (double)wk[d], cd);
      float twoC = (float)(2.0 * cd);
      float dist;
      {
#pragma clang fp contract(off)
        float t1 = A + wnp[k];
        dist = t1 - twoC;
      }
      if (dist < best || (dist == best && k < bk)) { best = dist; bk = k; }
    }
#pragma unroll
    for (int off = 1; off < 64; off <<= 1) {
      float ov = __shfl_xor(best, off, 64);
      int ok = __shfl_xor(bk, off, 64);
      if (ov < best || (ov == best && ok < bk)) { best = ov; bk = ok; }
    }

    int kold = (int)out[OUT_IDX_OFF + row];
    if (bk != kold) {
      float zv = zr[lane];
      float wN = W[(bk << 6) + lane];
      float oOld = out[(size_t)row * DD + lane];
      float tN = wN - zv;
      float oN = zv + tN;
      out[(size_t)row * DD + lane] = oN;
      float dN = zv - oN, dO = zv - oOld;
      float delta = dN * dN - dO * dO;
#pragma unroll
      for (int off = 1; off < 64; off <<= 1) delta += __shfl_xor(delta, off, 64);
      if (lane == 0) {
        atomicAdd(lossSum, delta);
        out[OUT_IDX_OFF + row] = (float)bk;
      }
    }
  }

  // fused finalize: last block to arrive writes the loss output
  __syncthreads();
  if (threadIdx.x == 0) {
    __threadfence();
    int old = atomicAdd(doneCnt, 1);
    if (old == (int)gridDim.x - 1) {
      __threadfence();
      float ls = atomicAdd(lossSum, 0.0f);  // device-scope read
      out[OUT_LOSS_OFF] = 0.25f * ls / (float)NELEM;
    }
  }
}

extern "C" void kernel_launch(void* const* d_in, const int* in_sizes, int n_in,
                              void* d_out, int out_size, void* d_ws, size_t ws_size,
                              hipStream_t stream) {
  const float* z = (const float*)d_in[0];
  const float* W = (const float*)d_in[1];
  float* out = (float*)d_out;
  char* ws = (char*)d_ws;

  int* flagCnt = (int*)(ws + WSO_CNT);
  float* lossSum = (float*)(ws + WSO_LOSS);
  int* doneCnt = (int*)(ws + WSO_DONE);
  float* wnorm = (float*)(ws + WSO_WNORM);
  int* flagList = (int*)(ws + WSO_LIST);

  hipMemsetAsync(d_ws, 0, 64, stream);  // zero flagCnt + lossSum + doneCnt

  k_main<<<NROWS / 128, 256, 0, stream>>>(z, W, out, wnorm, flagList, flagCnt, lossSum);
  k_refine<<<256, 256, 0, stream>>>(z, W, wnorm, out, flagList, flagCnt, lossSum, doneCnt);
}

// Round 5
// 208.713 us; speedup vs baseline: 1.1280x; 1.1280x over previous
//
#include <hip/hip_runtime.h>
#include <hip/hip_bf16.h>
#include <math.h>

#define NROWS 131072   // B*T = 32*4096
#define KC    512      // codebook size
#define DD    64       // embedding dim
#define NELEM (NROWS * DD)

#define OUT_IDX_OFF  NELEM
#define OUT_LOSS_OFF (NELEM + NROWS)

#define MARGIN 3e-5f   // identical to passing rounds 2-4

// d_ws byte offsets
#define WSO_CNT   0                        // int   flagged-row count
#define WSO_LOSS  8                        // float loss accumulator
#define WSO_DONE  16                       // int   refine done-counter
#define WSO_WNORM 64                       // float wnorm_np[512]
#define WSO_BH    4096                     // bf16 frags W-hi: 32t x 2kh x 64L x 8 = 64 KB
#define WSO_BL    (WSO_BH + 65536)         // bf16 frags W-lo: 64 KB
#define WSO_LIST  (WSO_BL + 65536)         // int flagList[NROWS]

typedef __attribute__((ext_vector_type(8))) short short8;
typedef __attribute__((ext_vector_type(4))) float f32x4;

// ---------------------------------------------------------------------------
// bf16 helpers (RNE via __float2bfloat16)
// ---------------------------------------------------------------------------
static __device__ __forceinline__ short f2bf(float f) {
  __hip_bfloat16 h = __float2bfloat16(f);
  short s; __builtin_memcpy(&s, &h, 2); return s;
}
static __device__ __forceinline__ float bf2f(short s) {
  unsigned u = ((unsigned)(unsigned short)s) << 16;
  float f; __builtin_memcpy(&f, &u, 4); return f;
}
// split 8 f32 into bf16 hi + bf16 lo(residual)
static __device__ __forceinline__ void split8(const float* v, short8& hi, short8& lo) {
#pragma unroll
  for (int j = 0; j < 8; j++) {
    float f = v[j];
    short hb = f2bf(f);
    float r = f - bf2f(hb);
    hi[j] = hb;
    lo[j] = f2bf(r);
  }
}

// ---------------------------------------------------------------------------
// numpy's pairwise sum of squares for 64 contiguous f32 (8-accumulator tree).
// contract(off) REQUIRED (hipcc default -ffp-contract=fast would fuse).
// ---------------------------------------------------------------------------
__device__ __forceinline__ float np_sumsq64(const float* __restrict__ p) {
#pragma clang fp contract(off)
  float r0 = p[0] * p[0], r1 = p[1] * p[1], r2 = p[2] * p[2], r3 = p[3] * p[3];
  float r4 = p[4] * p[4], r5 = p[5] * p[5], r6 = p[6] * p[6], r7 = p[7] * p[7];
  for (int i = 8; i < 64; i += 8) {
    r0 = r0 + p[i + 0] * p[i + 0];
    r1 = r1 + p[i + 1] * p[i + 1];
    r2 = r2 + p[i + 2] * p[i + 2];
    r3 = r3 + p[i + 3] * p[i + 3];
    r4 = r4 + p[i + 4] * p[i + 4];
    r5 = r5 + p[i + 5] * p[i + 5];
    r6 = r6 + p[i + 6] * p[i + 6];
    r7 = r7 + p[i + 7] * p[i + 7];
  }
  return ((r0 + r1) + (r2 + r3)) + ((r4 + r5) + (r6 + r7));
}

// ---------------------------------------------------------------------------
// Kernel 0: prep (verbatim from passing round 3). W -> B-fragment-major bf16
// hi/lo arrays + numpy-exact wnorm[512].
// Lane L of tile t, khalf h holds W[cw=t*16+(L&15)][d=32h+(L>>4)*8+j], j=0..7.
// ---------------------------------------------------------------------------
__global__ void k_prep(const float* __restrict__ W, short8* __restrict__ Bh,
                       short8* __restrict__ Bl, float* __restrict__ wnorm) {
  int gtid = blockIdx.x * blockDim.x + threadIdx.x;  // 0..4095
  int t = gtid >> 7, rem = gtid & 127;
  int h = rem >> 6, L = rem & 63;
  int cw = (t << 4) + (L & 15);
  int dbase = (h << 5) + ((L >> 4) << 3);
  const float* p = W + (cw << 6) + dbase;
  float4 u0 = *(const float4*)(p);
  float4 u1 = *(const float4*)(p + 4);
  float v[8] = {u0.x, u0.y, u0.z, u0.w, u1.x, u1.y, u1.z, u1.w};
  short8 hi, lo;
  split8(v, hi, lo);
  Bh[gtid] = hi;  // gtid == (t*2+h)*64 + L
  Bl[gtid] = lo;
  if (gtid < KC) wnorm[gtid] = np_sumsq64(W + (gtid << 6));
}

// ---------------------------------------------------------------------------
// Kernel 1 (k_main): MFMA screen + argmin + fused epilogue.
// 32 rows/wave (2 M-tiles) -> 4096 waves = 4 waves/SIMD, grid 1024 = 4 blk/CU.
// B frags streamed from prepped global arrays (128 KB, L2-hot). Screen math
// bit-identical to round 3 (same frags, same MFMA chain order, numpy wnorm).
// ---------------------------------------------------------------------------
__global__ __launch_bounds__(256) void k_main(
    const float* __restrict__ z, const float* __restrict__ W,
    const short8* __restrict__ Bh, const short8* __restrict__ Bl,
    const float* __restrict__ wnorm, float* __restrict__ out,
    int* __restrict__ flagList, int* __restrict__ flagCnt,
    float* __restrict__ lossSum) {
  const int lane = threadIdx.x & 63;
  const int wv = threadIdx.x >> 6;
  const int rowBase = blockIdx.x * 128 + wv * 32;
  const int m = lane & 15, quad = lane >> 4;

  // ---- A fragments: z hi/lo for 2 M-tiles x 2 k-halves ----
  short8 Ah[2][2], Al[2][2];
#pragma unroll
  for (int mt = 0; mt < 2; mt++) {
    const float* zp = z + (size_t)(rowBase + (mt << 4) + m) * DD + (quad << 3);
#pragma unroll
    for (int h = 0; h < 2; h++) {
      float4 u0 = *(const float4*)(zp + (h << 5));
      float4 u1 = *(const float4*)(zp + (h << 5) + 4);
      float v[8] = {u0.x, u0.y, u0.z, u0.w, u1.x, u1.y, u1.z, u1.w};
      split8(v, Ah[mt][h], Al[mt][h]);
    }
  }

  float b1[2][4], b2[2][4];
  int bi[2][4];
#pragma unroll
  for (int mt = 0; mt < 2; mt++)
#pragma unroll
    for (int r = 0; r < 4; r++) { b1[mt][r] = 1e30f; b2[mt][r] = 1e30f; bi[mt][r] = 0; }

  // ---- main loop over 32 codeword tiles ----
  for (int t = 0; t < 32; t++) {
    short8 Bhf[2], Blf[2];
#pragma unroll
    for (int h = 0; h < 2; h++) {
      Bhf[h] = Bh[((t * 2 + h) << 6) + lane];
      Blf[h] = Bl[((t * 2 + h) << 6) + lane];
    }
    float wn = wnorm[(t << 4) + m];

    f32x4 acc[2] = {{0.f, 0.f, 0.f, 0.f}, {0.f, 0.f, 0.f, 0.f}};
#pragma unroll
    for (int h = 0; h < 2; h++) {
#pragma unroll
      for (int mt = 0; mt < 2; mt++)
        acc[mt] = __builtin_amdgcn_mfma_f32_16x16x32_bf16(Ah[mt][h], Bhf[h], acc[mt], 0, 0, 0);
#pragma unroll
      for (int mt = 0; mt < 2; mt++)
        acc[mt] = __builtin_amdgcn_mfma_f32_16x16x32_bf16(Al[mt][h], Bhf[h], acc[mt], 0, 0, 0);
#pragma unroll
      for (int mt = 0; mt < 2; mt++)
        acc[mt] = __builtin_amdgcn_mfma_f32_16x16x32_bf16(Ah[mt][h], Blf[h], acc[mt], 0, 0, 0);
    }

    int colv = (t << 4) + m;
#pragma unroll
    for (int mt = 0; mt < 2; mt++)
#pragma unroll
      for (int r = 0; r < 4; r++) {
        float s = fmaf(-2.0f, acc[mt][r], wn);
        if (s < b1[mt][r]) { b2[mt][r] = b1[mt][r]; b1[mt][r] = s; bi[mt][r] = colv; }
        else b2[mt][r] = fminf(b2[mt][r], s);
      }
  }

  // ---- merge across the 16 col-lanes ----
#pragma unroll
  for (int off = 1; off < 16; off <<= 1) {
#pragma unroll
    for (int mt = 0; mt < 2; mt++)
#pragma unroll
      for (int r = 0; r < 4; r++) {
        float o1 = __shfl_xor(b1[mt][r], off, 64);
        float o2 = __shfl_xor(b2[mt][r], off, 64);
        int oi = __shfl_xor(bi[mt][r], off, 64);
        if (o1 < b1[mt][r] || (o1 == b1[mt][r] && oi < bi[mt][r])) {
          b2[mt][r] = fminf(b1[mt][r], o2);
          b1[mt][r] = o1; bi[mt][r] = oi;
        } else {
          b2[mt][r] = fminf(b2[mt][r], o1);
        }
      }
  }

  // ---- fused epilogue for this wave's 32 rows ----
  float lossAcc = 0.f;
#pragma unroll
  for (int mt = 0; mt < 2; mt++)
#pragma unroll
    for (int lr = 0; lr < 16; lr++) {
      const int q = lr >> 2, r = lr & 3;
      int ki = __shfl(bi[mt][r], q << 4, 64);
      float gap = b2[mt][r] - b1[mt][r];
      float gapr = __shfl(gap, q << 4, 64);
      int row = rowBase + (mt << 4) + lr;
      float zv = z[(size_t)row * DD + lane];
      float w = W[(ki << 6) + lane];
      float tt = w - zv;
      float o = zv + tt;  // matches reference z + (z_q - z)
      out[(size_t)row * DD + lane] = o;
      float dl = zv - o;
      lossAcc = fmaf(dl, dl, lossAcc);
      if (lane == 0) {
        out[OUT_IDX_OFF + row] = (float)ki;
        if (gapr < MARGIN) {
          int slot = atomicAdd(flagCnt, 1);
          flagList[slot] = row;
        }
      }
    }

#pragma unroll
  for (int off = 1; off < 64; off <<= 1) lossAcc += __shfl_xor(lossAcc, off, 64);
  if (lane == 0) atomicAdd(lossSum, lossAcc);
}

// ---------------------------------------------------------------------------
// Kernel 2 (k_refine): numpy-f32 replication for flagged rows + out/loss patch
// + fused loss finalize via done-counter (last block writes out[LOSS]).
// ---------------------------------------------------------------------------
__global__ void k_refine(const float* __restrict__ z, const float* __restrict__ W,
                         const float* __restrict__ wnp, float* __restrict__ out,
                         const int* __restrict__ flagList,
                         const int* __restrict__ flagCnt,
                         float* __restrict__ lossSum, int* __restrict__ doneCnt) {
  int nflag = *flagCnt;
  int lane = threadIdx.x & 63;
  int wave = (blockIdx.x * blockDim.x + threadIdx.x) >> 6;
  int nWaves = (gridDim.x * blockDim.x) >> 6;

  for (int f = wave; f < nflag; f += nWaves) {
    int row = flagList[f];
    const float* zr = z + (size_t)row * DD;
    float A = np_sumsq64(zr);

    float best = 1e30f;
    int bk = 0x7fffffff;
#pragma unroll
    for (int j = 0; j < KC / 64; j++) {
      int k = lane + (j << 6);
      const float* wk = W + (k << 6);
      double cd = 0.0;
      for (int d = 0; d < DD; d++) cd = fma((double)zr[d], (double)wk[d], cd);
      float twoC = (float)(2.0 * cd);
      float dist;
      {
#pragma clang fp contract(off)
        float t1 = A + wnp[k];
        dist = t1 - twoC;
      }
      if (dist < best || (dist == best && k < bk)) { best = dist; bk = k; }
    }
#pragma unroll
    for (int off = 1; off < 64; off <<= 1) {
      float ov = __shfl_xor(best, off, 64);
      int ok = __shfl_xor(bk, off, 64);
      if (ov < best || (ov == best && ok < bk)) { best = ov; bk = ok; }
    }

    int kold = (int)out[OUT_IDX_OFF + row];
    if (bk != kold) {
      float zv = zr[lane];
      float wN = W[(bk << 6) + lane];
      float oOld = out[(size_t)row * DD + lane];
      float tN = wN - zv;
      float oN = zv + tN;
      out[(size_t)row * DD + lane] = oN;
      float dN = zv - oN, dO = zv - oOld;
      float delta = dN * dN - dO * dO;
#pragma unroll
      for (int off = 1; off < 64; off <<= 1) delta += __shfl_xor(delta, off, 64);
      if (lane == 0) {
        atomicAdd(lossSum, delta);
        out[OUT_IDX_OFF + row] = (float)bk;
      }
    }
  }

  // fused finalize: last block to arrive writes the loss output
  __syncthreads();
  if (threadIdx.x == 0) {
    __threadfence();
    int old = atomicAdd(doneCnt, 1);
    if (old == (int)gridDim.x - 1) {
      __threadfence();
      float ls = atomicAdd(lossSum, 0.0f);  // device-scope read
      out[OUT_LOSS_OFF] = 0.25f * ls / (float)NELEM;
    }
  }
}

extern "C" void kernel_launch(void* const* d_in, const int* in_sizes, int n_in,
                              void* d_out, int out_size, void* d_ws, size_t ws_size,
                              hipStream_t stream) {
  const float* z = (const float*)d_in[0];
  const float* W = (const float*)d_in[1];
  float* out = (float*)d_out;
  char* ws = (char*)d_ws;

  int* flagCnt = (int*)(ws + WSO_CNT);
  float* lossSum = (float*)(ws + WSO_LOSS);
  int* doneCnt = (int*)(ws + WSO_DONE);
  float* wnorm = (float*)(ws + WSO_WNORM);
  short8* Bh = (short8*)(ws + WSO_BH);
  short8* Bl = (short8*)(ws + WSO_BL);
  int* flagList = (int*)(ws + WSO_LIST);

  hipMemsetAsync(d_ws, 0, 64, stream);  // zero flagCnt + lossSum + doneCnt

  k_prep<<<16, 256, 0, stream>>>(W, Bh, Bl, wnorm);
  k_main<<<NROWS / 128, 256, 0, stream>>>(z, W, Bh, Bl, wnorm, out,
                                          flagList, flagCnt, lossSum);
  k_refine<<<256, 256, 0, stream>>>(z, W, wnorm, out, flagList, flagCnt,
                                    lossSum, doneCnt);
}

// Round 6
// 202.951 us; speedup vs baseline: 1.1600x; 1.0284x over previous
//
#include <hip/hip_runtime.h>
#include <hip/hip_bf16.h>
#include <math.h>

#define NROWS 131072   // B*T = 32*4096
#define KC    512      // codebook size
#define DD    64       // embedding dim
#define NELEM (NROWS * DD)

#define OUT_IDX_OFF  NELEM
#define OUT_LOSS_OFF (NELEM + NROWS)

#define MARGIN 3e-5f   // identical to passing rounds 2-5

// d_ws byte offsets
#define WSO_CNT   0                        // int   flagged-row count
#define WSO_LOSS  8                        // float loss accumulator
#define WSO_DONE  16                       // int   refine done-counter
#define WSO_WNORM 64                       // float wnorm_np[512]
#define WSO_BH    4096                     // bf16 frags W-hi: 32t x 2kh x 64L x 8 = 64 KB
#define WSO_BL    (WSO_BH + 65536)         // bf16 frags W-lo: 64 KB
#define WSO_LIST  (WSO_BL + 65536)         // int flagList[NROWS]

typedef __attribute__((ext_vector_type(8))) short short8;
typedef __attribute__((ext_vector_type(4))) float f32x4;

// ---------------------------------------------------------------------------
// bf16 helpers (RNE via __float2bfloat16)
// ---------------------------------------------------------------------------
static __device__ __forceinline__ short f2bf(float f) {
  __hip_bfloat16 h = __float2bfloat16(f);
  short s; __builtin_memcpy(&s, &h, 2); return s;
}
static __device__ __forceinline__ float bf2f(short s) {
  unsigned u = ((unsigned)(unsigned short)s) << 16;
  float f; __builtin_memcpy(&f, &u, 4); return f;
}
// split 8 f32 into bf16 hi + bf16 lo(residual)
static __device__ __forceinline__ void split8(const float* v, short8& hi, short8& lo) {
#pragma unroll
  for (int j = 0; j < 8; j++) {
    float f = v[j];
    short hb = f2bf(f);
    float r = f - bf2f(hb);
    hi[j] = hb;
    lo[j] = f2bf(r);
  }
}

// ---------------------------------------------------------------------------
// numpy's pairwise sum of squares for 64 contiguous f32 (8-accumulator tree).
// contract(off) REQUIRED (hipcc default -ffp-contract=fast would fuse).
// ---------------------------------------------------------------------------
__device__ __forceinline__ float np_sumsq64(const float* __restrict__ p) {
#pragma clang fp contract(off)
  float r0 = p[0] * p[0], r1 = p[1] * p[1], r2 = p[2] * p[2], r3 = p[3] * p[3];
  float r4 = p[4] * p[4], r5 = p[5] * p[5], r6 = p[6] * p[6], r7 = p[7] * p[7];
  for (int i = 8; i < 64; i += 8) {
    r0 = r0 + p[i + 0] * p[i + 0];
    r1 = r1 + p[i + 1] * p[i + 1];
    r2 = r2 + p[i + 2] * p[i + 2];
    r3 = r3 + p[i + 3] * p[i + 3];
    r4 = r4 + p[i + 4] * p[i + 4];
    r5 = r5 + p[i + 5] * p[i + 5];
    r6 = r6 + p[i + 6] * p[i + 6];
    r7 = r7 + p[i + 7] * p[i + 7];
  }
  return ((r0 + r1) + (r2 + r3)) + ((r4 + r5) + (r6 + r7));
}

// ---------------------------------------------------------------------------
// Kernel 0: prep (verbatim from passing rounds). W -> B-fragment-major bf16
// hi/lo arrays + numpy-exact wnorm[512].
// Lane L of tile t, khalf h holds W[cw=t*16+(L&15)][d=32h+(L>>4)*8+j], j=0..7.
// ---------------------------------------------------------------------------
__global__ void k_prep(const float* __restrict__ W, short8* __restrict__ Bh,
                       short8* __restrict__ Bl, float* __restrict__ wnorm) {
  int gtid = blockIdx.x * blockDim.x + threadIdx.x;  // 0..4095
  int t = gtid >> 7, rem = gtid & 127;
  int h = rem >> 6, L = rem & 63;
  int cw = (t << 4) + (L & 15);
  int dbase = (h << 5) + ((L >> 4) << 3);
  const float* p = W + (cw << 6) + dbase;
  float4 u0 = *(const float4*)(p);
  float4 u1 = *(const float4*)(p + 4);
  float v[8] = {u0.x, u0.y, u0.z, u0.w, u1.x, u1.y, u1.z, u1.w};
  short8 hi, lo;
  split8(v, hi, lo);
  Bh[gtid] = hi;  // gtid == (t*2+h)*64 + L
  Bl[gtid] = lo;
  if (gtid < KC) wnorm[gtid] = np_sumsq64(W + (gtid << 6));
}

// ---------------------------------------------------------------------------
// Kernel 1 (k_main): MFMA screen + argmin + fused epilogue, LDS-staged B.
// 32 rows/wave, 128 rows/block, grid 1024 = 4 blocks/CU.
// B frags + wnorm double-buffered in LDS (chunks of 4 tiles = 16.25 KB/buf);
// staging for chunk c+1 issued before computing chunk c. Inner loop has zero
// global loads. Screen math bit-identical to rounds 3/5 (same frag bits, same
// MFMA chain order, same numpy wnorm).
// LDS buffer layout (float4 units, per buffer of 1040):
//   [0..511]    Bh granules: (tc*2+h)*64+lane
//   [512..1023] Bl granules
//   [1024..1039] wn: 64 floats (tc*16+m)
// ---------------------------------------------------------------------------
__global__ __launch_bounds__(256, 4) void k_main(
    const float* __restrict__ z, const float* __restrict__ W,
    const short8* __restrict__ Bh, const short8* __restrict__ Bl,
    const float* __restrict__ wnorm, float* __restrict__ out,
    int* __restrict__ flagList, int* __restrict__ flagCnt,
    float* __restrict__ lossSum) {
  const int tid = threadIdx.x;
  const int lane = tid & 63;
  const int wv = tid >> 6;
  const int rowBase = blockIdx.x * 128 + wv * 32;
  const int m = lane & 15, quad = lane >> 4;

  __shared__ float4 ldsBuf[2080];  // 2 x 1040 x 16 B = 33280 B

  // ---- A fragments: z hi/lo for 2 M-tiles x 2 k-halves ----
  short8 Ah[2][2], Al[2][2];
#pragma unroll
  for (int mt = 0; mt < 2; mt++) {
    const float* zp = z + (size_t)(rowBase + (mt << 4) + m) * DD + (quad << 3);
#pragma unroll
    for (int h = 0; h < 2; h++) {
      float4 u0 = *(const float4*)(zp + (h << 5));
      float4 u1 = *(const float4*)(zp + (h << 5) + 4);
      float v[8] = {u0.x, u0.y, u0.z, u0.w, u1.x, u1.y, u1.z, u1.w};
      split8(v, Ah[mt][h], Al[mt][h]);
    }
  }

  float b1[2][4], b2[2][4];
  int bi[2][4];
#pragma unroll
  for (int mt = 0; mt < 2; mt++)
#pragma unroll
    for (int r = 0; r < 4; r++) { b1[mt][r] = 1e30f; b2[mt][r] = 1e30f; bi[mt][r] = 0; }

  const float4* gBh = (const float4*)Bh;
  const float4* gBl = (const float4*)Bl;
  const float4* gWn = (const float4*)wnorm;

  // stage chunk 0 into buffer 0
  float4 nr0, nr1, nr2, nr3, nr4;
  nr0 = gBh[tid];        nr1 = gBh[tid + 256];
  nr2 = gBl[tid];        nr3 = gBl[tid + 256];
  if (tid < 16) nr4 = gWn[tid];
  ldsBuf[tid] = nr0;        ldsBuf[tid + 256] = nr1;
  ldsBuf[512 + tid] = nr2;  ldsBuf[512 + tid + 256] = nr3;
  if (tid < 16) ldsBuf[1024 + tid] = nr4;
  __syncthreads();

  // ---- main loop: 8 chunks x 4 tiles ----
  for (int c = 0; c < 8; c++) {
    const int b = c & 1;
    if (c < 7) {  // issue next-chunk global loads early (latency hidden by compute)
      const int g = (c + 1) << 9;
      nr0 = gBh[g + tid];        nr1 = gBh[g + tid + 256];
      nr2 = gBl[g + tid];        nr3 = gBl[g + tid + 256];
      if (tid < 16) nr4 = gWn[((c + 1) << 4) + tid];
    }

    const float4* L = ldsBuf + b * 1040;
#pragma unroll
    for (int tc = 0; tc < 4; tc++) {
      short8 Bhf[2], Blf[2];
#pragma unroll
      for (int h = 0; h < 2; h++) {
        Bhf[h] = *(const short8*)&L[((tc * 2 + h) << 6) + lane];
        Blf[h] = *(const short8*)&L[512 + ((tc * 2 + h) << 6) + lane];
      }
      float wn = ((const float*)&L[1024])[(tc << 4) + m];

      f32x4 acc[2] = {{0.f, 0.f, 0.f, 0.f}, {0.f, 0.f, 0.f, 0.f}};
#pragma unroll
      for (int h = 0; h < 2; h++) {
#pragma unroll
        for (int mt = 0; mt < 2; mt++)
          acc[mt] = __builtin_amdgcn_mfma_f32_16x16x32_bf16(Ah[mt][h], Bhf[h], acc[mt], 0, 0, 0);
#pragma unroll
        for (int mt = 0; mt < 2; mt++)
          acc[mt] = __builtin_amdgcn_mfma_f32_16x16x32_bf16(Al[mt][h], Bhf[h], acc[mt], 0, 0, 0);
#pragma unroll
        for (int mt = 0; mt < 2; mt++)
          acc[mt] = __builtin_amdgcn_mfma_f32_16x16x32_bf16(Ah[mt][h], Blf[h], acc[mt], 0, 0, 0);
      }

      int colv = (((c << 2) + tc) << 4) + m;
#pragma unroll
      for (int mt = 0; mt < 2; mt++)
#pragma unroll
        for (int r = 0; r < 4; r++) {
          float s = fmaf(-2.0f, acc[mt][r], wn);
          if (s < b1[mt][r]) { b2[mt][r] = b1[mt][r]; b1[mt][r] = s; bi[mt][r] = colv; }
          else b2[mt][r] = fminf(b2[mt][r], s);
        }
    }

    if (c < 7) {  // write next chunk into the other buffer
      float4* Ld = ldsBuf + (1 - b) * 1040;
      Ld[tid] = nr0;        Ld[tid + 256] = nr1;
      Ld[512 + tid] = nr2;  Ld[512 + tid + 256] = nr3;
      if (tid < 16) Ld[1024 + tid] = nr4;
    }
    __syncthreads();
  }

  // ---- merge across the 16 col-lanes ----
#pragma unroll
  for (int off = 1; off < 16; off <<= 1) {
#pragma unroll
    for (int mt = 0; mt < 2; mt++)
#pragma unroll
      for (int r = 0; r < 4; r++) {
        float o1 = __shfl_xor(b1[mt][r], off, 64);
        float o2 = __shfl_xor(b2[mt][r], off, 64);
        int oi = __shfl_xor(bi[mt][r], off, 64);
        if (o1 < b1[mt][r] || (o1 == b1[mt][r] && oi < bi[mt][r])) {
          b2[mt][r] = fminf(b1[mt][r], o2);
          b1[mt][r] = o1; bi[mt][r] = oi;
        } else {
          b2[mt][r] = fminf(b2[mt][r], o1);
        }
      }
  }

  // ---- fused epilogue for this wave's 32 rows ----
  float lossAcc = 0.f;
#pragma unroll
  for (int mt = 0; mt < 2; mt++)
#pragma unroll
    for (int lr = 0; lr < 16; lr++) {
      const int q = lr >> 2, r = lr & 3;
      int ki = __shfl(bi[mt][r], q << 4, 64);
      float gap = b2[mt][r] - b1[mt][r];
      float gapr = __shfl(gap, q << 4, 64);
      int row = rowBase + (mt << 4) + lr;
      float zv = z[(size_t)row * DD + lane];
      float w = W[(ki << 6) + lane];
      float tt = w - zv;
      float o = zv + tt;  // matches reference z + (z_q - z)
      out[(size_t)row * DD + lane] = o;
      float dl = zv - o;
      lossAcc = fmaf(dl, dl, lossAcc);
      if (lane == 0) {
        out[OUT_IDX_OFF + row] = (float)ki;
        if (gapr < MARGIN) {
          int slot = atomicAdd(flagCnt, 1);
          flagList[slot] = row;
        }
      }
    }

#pragma unroll
  for (int off = 1; off < 64; off <<= 1) lossAcc += __shfl_xor(lossAcc, off, 64);
  if (lane == 0) atomicAdd(lossSum, lossAcc);
}

// ---------------------------------------------------------------------------
// Kernel 2 (k_refine): numpy-f32 replication for flagged rows + out/loss patch
// + fused loss finalize via done-counter (last block writes out[LOSS]).
// ---------------------------------------------------------------------------
__global__ void k_refine(const float* __restrict__ z, const float* __restrict__ W,
                         const float* __restrict__ wnp, float* __restrict__ out,
                         const int* __restrict__ flagList,
                         const int* __restrict__ flagCnt,
                         float* __restrict__ lossSum, int* __restrict__ doneCnt) {
  int nflag = *flagCnt;
  int lane = threadIdx.x & 63;
  int wave = (blockIdx.x * blockDim.x + threadIdx.x) >> 6;
  int nWaves = (gridDim.x * blockDim.x) >> 6;

  for (int f = wave; f < nflag; f += nWaves) {
    int row = flagList[f];
    const float* zr = z + (size_t)row * DD;
    float A = np_sumsq64(zr);

    float best = 1e30f;
    int bk = 0x7fffffff;
#pragma unroll
    for (int j = 0; j < KC / 64; j++) {
      int k = lane + (j << 6);
      const float* wk = W + (k << 6);
      double cd = 0.0;
      for (int d = 0; d < DD; d++) cd = fma((double)zr[d], (double)wk[d], cd);
      float twoC = (float)(2.0 * cd);
      float dist;
      {
#pragma clang fp contract(off)
        float t1 = A + wnp[k];
        dist = t1 - twoC;
      }
      if (dist < best || (dist == best && k < bk)) { best = dist; bk = k; }
    }
#pragma unroll
    for (int off = 1; off < 64; off <<= 1) {
      float ov = __shfl_xor(best, off, 64);
      int ok = __shfl_xor(bk, off, 64);
      if (ov < best || (ov == best && ok < bk)) { best = ov; bk = ok; }
    }

    int kold = (int)out[OUT_IDX_OFF + row];
    if (bk != kold) {
      float zv = zr[lane];
      float wN = W[(bk << 6) + lane];
      float oOld = out[(size_t)row * DD + lane];
      float tN = wN - zv;
      float oN = zv + tN;
      out[(size_t)row * DD + lane] = oN;
      float dN = zv - oN, dO = zv - oOld;
      float delta = dN * dN - dO * dO;
#pragma unroll
      for (int off = 1; off < 64; off <<= 1) delta += __shfl_xor(delta, off, 64);
      if (lane == 0) {
        atomicAdd(lossSum, delta);
        out[OUT_IDX_OFF + row] = (float)bk;
      }
    }
  }

  // fused finalize: last block to arrive writes the loss output
  __syncthreads();
  if (threadIdx.x == 0) {
    __threadfence();
    int old = atomicAdd(doneCnt, 1);
    if (old == (int)gridDim.x - 1) {
      __threadfence();
      float ls = atomicAdd(lossSum, 0.0f);  // device-scope read
      out[OUT_LOSS_OFF] = 0.25f * ls / (float)NELEM;
    }
  }
}

extern "C" void kernel_launch(void* const* d_in, const int* in_sizes, int n_in,
                              void* d_out, int out_size, void* d_ws, size_t ws_size,
                              hipStream_t stream) {
  const float* z = (const float*)d_in[0];
  const float* W = (const float*)d_in[1];
  float* out = (float*)d_out;
  char* ws = (char*)d_ws;

  int* flagCnt = (int*)(ws + WSO_CNT);
  float* lossSum = (float*)(ws + WSO_LOSS);
  int* doneCnt = (int*)(ws + WSO_DONE);
  float* wnorm = (float*)(ws + WSO_WNORM);
  short8* Bh = (short8*)(ws + WSO_BH);
  short8* Bl = (short8*)(ws + WSO_BL);
  int* flagList = (int*)(ws + WSO_LIST);

  hipMemsetAsync(d_ws, 0, 64, stream);  // zero flagCnt + lossSum + doneCnt

  k_prep<<<16, 256, 0, stream>>>(W, Bh, Bl, wnorm);
  k_main<<<NROWS / 128, 256, 0, stream>>>(z, W, Bh, Bl, wnorm, out,
                                          flagList, flagCnt, lossSum);
  k_refine<<<256, 256, 0, stream>>>(z, W, wnorm, out, flagList, flagCnt,
                                    lossSum, doneCnt);
}